// Round 5
// baseline (213.939 us; speedup 1.0000x reference)
//
#include <hip/hip_runtime.h>
#include <hip/hip_cooperative_groups.h>
#include <stdint.h>

namespace cg = cooperative_groups;

#define NB 8
#define NS 256
#define ND 1024
#define EPSF 1e-5f
#define BIGF 3.0e38f

typedef __attribute__((ext_vector_type(8))) short short8;
typedef __attribute__((ext_vector_type(4))) float f32x4;

__device__ __forceinline__ unsigned short f2bf(float f) {
  unsigned int u = __float_as_uint(f);
  u = (u + 0x7FFFu + ((u >> 16) & 1u)) >> 16;
  return (unsigned short)u;
}

// Single cooperative kernel: 256 blocks x 256 threads, 4 phases, 3 grid syncs.
__global__ __launch_bounds__(256) void k_fused(const float* __restrict__ x,
                                               unsigned short* __restrict__ Xb,
                                               unsigned short* __restrict__ Yb,
                                               float* __restrict__ C,
                                               float* __restrict__ S2,
                                               float* __restrict__ DGa,
                                               float* __restrict__ IXa,
                                               float* __restrict__ out) {
  __shared__ float As[64][36];   // phase-4 only
  __shared__ float Bs[64][68];
  __shared__ float wred[4];
  cg::grid_group grid = cg::this_grid();

  int blk = blockIdx.x;
  int tid = threadIdx.x;
  int wv = tid >> 6;
  int lane = tid & 63;
  int wid = blk * 4 + wv;        // 0..1023

  // ---------------- Phase 1: convert + diag + ypfx + zero C row0 ----------------
  // convert: 2 rows per wave (2048 rows total)
#pragma unroll
  for (int rr = 0; rr < 2; ++rr) {
    int row = blk * 8 + wv * 2 + rr;
    size_t base = (size_t)row * ND;
    float sq = 0.f;
#pragma unroll
    for (int c = 0; c < 4; ++c) {
      size_t o = base + c * 256 + lane * 4;
      float4 v = *reinterpret_cast<const float4*>(x + o);
      ushort4 ob;
      ob.x = f2bf(v.x); ob.y = f2bf(v.y); ob.z = f2bf(v.z); ob.w = f2bf(v.w);
      *reinterpret_cast<ushort4*>(Xb + o) = ob;
      sq += v.x * v.x + v.y * v.y + v.z * v.z + v.w * v.w;
    }
#pragma unroll
    for (int off = 32; off; off >>= 1) sq += __shfl_xor(sq, off);
    if (lane == 0) {
      DGa[row] = sq;
      IXa[row] = 1.0f / sqrtf(sq);   // inf if 0 -> forces slow path
    }
  }
  // zero C row 0 of each batch
  if (blk < NB) C[(size_t)blk * 257 * NS + tid] = 0.f;
  // ypfx: 8 columns per wave, read fp32 x directly (no dependency on convert)
#pragma unroll
  for (int c = 0; c < 8; ++c) {
    int g = wid * 8 + c;              // 0..8191
    int b = g >> 10;
    int d = g & 1023;
    const float* xr = x + ((size_t)b << 18) + d;
    unsigned short* yr = Yb + ((size_t)b << 18) + d;
    int s0 = lane << 2;
    float v0 = xr[(size_t)(s0 + 0) * ND];
    float v1 = xr[(size_t)(s0 + 1) * ND];
    float v2 = xr[(size_t)(s0 + 2) * ND];
    float v3 = xr[(size_t)(s0 + 3) * ND];
    float sum = v0 + v1 + v2 + v3;
    float sc = sum;
#pragma unroll
    for (int off = 1; off < 64; off <<= 1) {
      float n = __shfl_up(sc, off);
      if (lane >= off) sc += n;
    }
    float y0 = (sc - sum) + v0;
    float y1 = y0 + v1;
    float y2 = y1 + v2;
    float y3 = y2 + v3;
    yr[(size_t)(s0 + 0) * ND] = f2bf(y0);
    yr[(size_t)(s0 + 1) * ND] = f2bf(y1);
    yr[(size_t)(s0 + 2) * ND] = f2bf(y2);
    yr[(size_t)(s0 + 3) * ND] = f2bf(y3);
  }

  grid.sync();

  // ---------------- Phase 2: C[r,t] = Y_{r-1} . x_t  (16x16 tiles, K=1024) ----------------
  {
    int lr = lane & 15;
    int lk = (lane >> 4) << 3;
#pragma unroll
    for (int jj = 0; jj < 2; ++jj) {
      int job = wid * 2 + jj;          // 0..2047
      int b = job >> 8;
      int mt = (job >> 4) & 15;
      int nt = job & 15;
      const unsigned short* Ab = Yb + ((size_t)b << 18) + ((size_t)(mt << 4) << 10);
      const unsigned short* Bb = Xb + ((size_t)b << 18) + ((size_t)(nt << 4) << 10);
      f32x4 acc = {0.f, 0.f, 0.f, 0.f};
#pragma unroll 4
      for (int kk = 0; kk < 1024; kk += 32) {
        short8 a  = *reinterpret_cast<const short8*>(Ab + ((size_t)lr << 10) + kk + lk);
        short8 bv = *reinterpret_cast<const short8*>(Bb + ((size_t)lr << 10) + kk + lk);
        acc = __builtin_amdgcn_mfma_f32_16x16x32_bf16(a, bv, acc, 0, 0, 0);
      }
      // C/D layout: col = lane&15, row = (lane>>4)*4 + j   [measured m89]
      float* Cb = C + (size_t)b * 257 * NS;
      int r0 = (mt << 4) + ((lane >> 4) << 2) + 1;   // +1: C row r = tile row rr+1
      int c0 = (nt << 4) + lr;
#pragma unroll
      for (int j = 0; j < 4; ++j) Cb[(size_t)(r0 + j) * NS + c0] = acc[j];
    }
  }

  grid.sync();

  // ---------------- Phase 3: S2[r,c] = prefix of C row r ----------------
#pragma unroll
  for (int p = 0; p < 3; ++p) {
    int id = wid + p * 1024;           // 0..2055
    if (id < NB * 257) {
      int b = id / 257;
      int r = id - b * 257;
      const float* Crow = C + ((size_t)b * 257 + r) * NS;
      float* Srow = S2 + ((size_t)b * 257 + r) * 257;
      if (lane == 0) Srow[0] = 0.f;
      float run = 0.f;
      for (int c0 = 0; c0 < NS; c0 += 64) {
        float v = Crow[c0 + lane];
#pragma unroll
        for (int off = 1; off < 64; off <<= 1) {
          float n = __shfl_up(v, off);
          if (lane >= off) v += n;
        }
        Srow[c0 + lane + 1] = run + v;
        run += __shfl(v, 63);
      }
    }
  }

  grid.sync();

  // ---------------- Phase 4: tropical min + epilogue (one 32x64 tile per block) ----------------
  {
    int b = blk >> 5;
    int tix = blk & 31;
    int i0 = (tix >> 2) << 5;
    int j0 = (tix & 3) << 6;
    float* outb = out + ((size_t)b << 16);

    if (i0 >= j0 + 63) {               // fully-invalid tile: zero-fill
      float4 z = {0.f, 0.f, 0.f, 0.f};
      float* p = outb + (size_t)(i0 + (tid >> 3)) * NS + j0 + ((tid & 7) << 3);
      reinterpret_cast<float4*>(p)[0] = z;
      reinterpret_cast<float4*>(p)[1] = z;
      return;
    }

    const float* Cb = C + (size_t)b * 257 * NS;
    const float* IXb = IXa + b * NS;

    float wv0 = IXb[tid];
#pragma unroll
    for (int off = 32; off; off >>= 1) wv0 = fmaxf(wv0, __shfl_xor(wv0, off));
    if ((tid & 63) == 0) wred[tid >> 6] = wv0;
    __syncthreads();
    float wmb = fmaxf(fmaxf(wred[0], wred[1]), fmaxf(wred[2], wred[3]));

    int ii0 = (tid >> 4) << 1;
    int jj0 = (tid & 15) << 2;
    float acc[8];
#pragma unroll
    for (int k = 0; k < 8; ++k) acc[k] = BIGF;

    int rA = tid >> 4;
    int c4 = (tid & 15) << 2;

    for (int t0 = i0 & ~63; t0 < j0 + 64; t0 += 64) {
      __syncthreads();
      float4 wv4 = *reinterpret_cast<const float4*>(IXb + t0 + c4);
#pragma unroll
      for (int p = 0; p < 2; ++p) {
        int r = i0 + p * 16 + rA;
        float4 v = *reinterpret_cast<const float4*>(Cb + (size_t)r * NS + t0 + c4);
        As[c4 + 0][p * 16 + rA] = v.x * wv4.x;
        As[c4 + 1][p * 16 + rA] = v.y * wv4.y;
        As[c4 + 2][p * 16 + rA] = v.z * wv4.z;
        As[c4 + 3][p * 16 + rA] = v.w * wv4.w;
      }
#pragma unroll
      for (int p = 0; p < 4; ++p) {
        int r = j0 + 1 + p * 16 + rA;
        float4 v = *reinterpret_cast<const float4*>(Cb + (size_t)r * NS + t0 + c4);
        Bs[c4 + 0][p * 16 + rA] = v.x * wv4.x;
        Bs[c4 + 1][p * 16 + rA] = v.y * wv4.y;
        Bs[c4 + 2][p * 16 + rA] = v.z * wv4.z;
        Bs[c4 + 3][p * 16 + rA] = v.w * wv4.w;
      }
      __syncthreads();

      int thA = i0 + ii0 - t0;
      int thB = j0 + jj0 - t0;
      if (thA <= -1 && thB >= 63) {
#pragma unroll 4
        for (int tt = 0; tt < 64; ++tt) {
          float2 a = *reinterpret_cast<const float2*>(&As[tt][ii0]);
          float4 bv = *reinterpret_cast<const float4*>(&Bs[tt][jj0]);
          acc[0] = fminf(acc[0], bv.x - a.x);
          acc[1] = fminf(acc[1], bv.y - a.x);
          acc[2] = fminf(acc[2], bv.z - a.x);
          acc[3] = fminf(acc[3], bv.w - a.x);
          acc[4] = fminf(acc[4], bv.x - a.y);
          acc[5] = fminf(acc[5], bv.y - a.y);
          acc[6] = fminf(acc[6], bv.z - a.y);
          acc[7] = fminf(acc[7], bv.w - a.y);
        }
      } else {
#pragma unroll 4
        for (int tt = 0; tt < 64; ++tt) {
          float2 a = *reinterpret_cast<const float2*>(&As[tt][ii0]);
          float4 bv = *reinterpret_cast<const float4*>(&Bs[tt][jj0]);
          float a0 = (tt >= thA)     ? a.x  : -BIGF;
          float a1 = (tt >= thA + 1) ? a.y  : -BIGF;
          float b0 = (tt <= thB)     ? bv.x :  BIGF;
          float b1 = (tt <= thB + 1) ? bv.y :  BIGF;
          float b2 = (tt <= thB + 2) ? bv.z :  BIGF;
          float b3 = (tt <= thB + 3) ? bv.w :  BIGF;
          acc[0] = fminf(acc[0], b0 - a0);
          acc[1] = fminf(acc[1], b1 - a0);
          acc[2] = fminf(acc[2], b2 - a0);
          acc[3] = fminf(acc[3], b3 - a0);
          acc[4] = fminf(acc[4], b0 - a1);
          acc[5] = fminf(acc[5], b1 - a1);
          acc[6] = fminf(acc[6], b2 - a1);
          acc[7] = fminf(acc[7], b3 - a1);
        }
      }
    }

    const float* S2b = S2 + (size_t)b * 257 * 257;
    const float* DGb = DGa + b * NS;
#pragma unroll
    for (int k = 0; k < 2; ++k) {
      int i = i0 + ii0 + k;
      float o4[4];
      float s2ii = S2b[(size_t)i * 257 + i];
#pragma unroll
      for (int l = 0; l < 4; ++l) {
        int j = j0 + jj0 + l;
        float res = 0.f;
        if (i >= 1 && j > i) {
          float s2jj = S2b[(size_t)(j + 1) * 257 + (j + 1)];
          float s2ij = S2b[(size_t)i * 257 + (j + 1)];
          float s2ji = S2b[(size_t)(j + 1) * 257 + i];
          float ssq = (s2jj - s2ij) - (s2ji - s2ii);
          float sn = sqrtf(fmaxf(ssq, 0.f));
          float win = (float)(j - i + 1);
          if (sn >= EPSF * win * wmb) {
            res = acc[k * 4 + l] / sn;             // fast path: EPS never binds
          } else {
            float mn = sn / win;
            float m = BIGF;
            const float* r2 = Cb + (size_t)(j + 1) * NS;
            const float* r1 = Cb + (size_t)i * NS;
            for (int t = i; t <= j; ++t) {
              float num = r2[t] - r1[t];
              float xn = sqrtf(fmaxf(DGb[t], 0.f));
              float den = fmaxf(mn * xn, EPSF);
              m = fminf(m, num / win / den);
            }
            res = m;
          }
        }
        o4[l] = res;
      }
      float4 st = {o4[0], o4[1], o4[2], o4[3]};
      *reinterpret_cast<float4*>(outb + (size_t)i * NS + j0 + jj0) = st;
    }
  }
}

extern "C" void kernel_launch(void* const* d_in, const int* in_sizes, int n_in,
                              void* d_out, int out_size, void* d_ws, size_t ws_size,
                              hipStream_t stream) {
  (void)in_sizes; (void)n_in; (void)ws_size; (void)out_size;
  const float* x = (const float*)d_in[0];
  float* out = (float*)d_out;
  char* ws = (char*)d_ws;
  unsigned short* Xb = (unsigned short*)(ws);                 //  4,194,304 B
  unsigned short* Yb = (unsigned short*)(ws + 4194304);       //  4,194,304 B
  float* C   = (float*)(ws + 8388608);                        //  2,105,344 B (8 x 257 x 256)
  float* S2  = (float*)(ws + 10493952);                       //  2,113,568 B (8 x 257 x 257)
  float* DGa = (float*)(ws + 12607520);                       //  8,192 B
  float* IXa = (float*)(ws + 12615712);                       //  8,192 B

  void* args[] = {(void*)&x, (void*)&Xb, (void*)&Yb, (void*)&C, (void*)&S2,
                  (void*)&DGa, (void*)&IXa, (void*)&out};
  hipLaunchCooperativeKernel((void*)k_fused, dim3(256), dim3(256), args, 0, stream);
}